// Round 16
// baseline (310.524 us; speedup 1.0000x reference)
//
#include <hip/hip_runtime.h>
#include <hip/hip_cooperative_groups.h>
#include <math.h>

namespace cg = cooperative_groups;

#define NNODES 50000
#define D 256
#define NSAMP 5
#define LN_EPS 1e-5f
#define NB 196           // row buckets of 256 rows: ceil(50000/256)
#define BCAP 9216        // edges per bucket capacity (mean 8192, +11 sigma)
#define ACHUNK 8192      // edges per binA unit

typedef __bf16 bf16;
typedef __attribute__((ext_vector_type(8))) __bf16 bf16x8;
typedef __attribute__((ext_vector_type(4))) float f32x4;
typedef unsigned long long u64;
typedef unsigned int u32;

__device__ inline float bflo(u32 u) { return __uint_as_float(u << 16); }
__device__ inline float bfhi(u32 u) { return __uint_as_float(u & 0xffff0000u); }

__device__ inline u64 packrec(int r, int c, float v) {
    // col:16 | row:16 | valbits:32   (N=50000 < 65536 so both fit 16 bits)
    return (u64)(u32)(c | (r << 16)) | ((u64)__float_as_uint(v) << 32);
}

// ---------------------------------------------------------------------------
// device phase bodies (shared by mega kernel and fallback wrappers)
// ---------------------------------------------------------------------------
__device__ void dev_prep_unit(int u, const float* __restrict__ w,
                              bf16* __restrict__ wt, int* __restrict__ bcur) {
    __shared__ float t[64][65];
    const int tid = threadIdx.x;
    __syncthreads();
    if (u < 16) {
        const int bi = u >> 2, bj = u & 3;
#pragma unroll
        for (int it = 0; it < 16; ++it) {
            const int krow = (tid >> 6) + it * 4;
            t[krow][tid & 63] = w[(size_t)(bi * 64 + krow) * D + (bj * 64 + (tid & 63))];
        }
        __syncthreads();
#pragma unroll
        for (int it = 0; it < 16; ++it) {
            const int nrow = (tid >> 6) + it * 4;
            wt[(size_t)(bj * 64 + nrow) * D + (bi * 64 + (tid & 63))] = (bf16)t[tid & 63][nrow];
        }
        __syncthreads();
    } else {
        bcur[tid] = 0;   // u == 16: zero 256 bucket cursors
    }
}

__device__ void dev_binA(int u, const int* __restrict__ rows, const int* __restrict__ cols,
                         const float* __restrict__ vals, int* __restrict__ bcur,
                         u64* __restrict__ binned, int E) {
    __shared__ int histA[NB];
    __shared__ int baseA[NB];
    __syncthreads();
    for (int i = threadIdx.x; i < NB; i += 256) histA[i] = 0;
    __syncthreads();
    const int e0 = u * ACHUNK;
    const int e1 = min(e0 + ACHUNK, E);
    for (int e = e0 + threadIdx.x; e < e1; e += 256)
        atomicAdd(&histA[rows[e] >> 8], 1);
    __syncthreads();
    for (int i = threadIdx.x; i < NB; i += 256) {
        const int c = histA[i];
        baseA[i] = c ? atomicAdd(&bcur[i], c) : 0;
        histA[i] = 0;                      // reuse as local cursor
    }
    __syncthreads();
    for (int e = e0 + threadIdx.x; e < e1; e += 256) {
        const int r = rows[e];
        const int b = r >> 8;
        const int k = baseA[b] + atomicAdd(&histA[b], 1);
        if (k < BCAP)                      // statistically unreachable guard
            binned[(size_t)b * BCAP + k] = packrec(r, cols[e], vals[e]);
    }
}

__device__ void dev_gemm(int gb, const float* __restrict__ x,
                         const bf16* __restrict__ wt, bf16* __restrict__ h) {
    const int wave = threadIdx.x >> 6;
    const int lane = threadIdx.x & 63;
    const int row0 = gb * 64 + wave * 16;
    const int am = lane & 15;
    const int ag = lane >> 4;

    int arow = row0 + am;
    if (arow >= NNODES) arow = NNODES - 1;

    f32x4 acc[16];
#pragma unroll
    for (int n = 0; n < 16; ++n) acc[n] = (f32x4){0.f, 0.f, 0.f, 0.f};

#pragma unroll
    for (int kk = 0; kk < 8; ++kk) {
        const int kb = kk * 32 + ag * 8;
        const float* xp = x + (size_t)arow * D + kb;
        const f32x4 a0 = __builtin_nontemporal_load((const f32x4*)xp);
        const f32x4 a1 = __builtin_nontemporal_load((const f32x4*)(xp + 4));
        bf16x8 a;
        a[0] = (bf16)a0[0]; a[1] = (bf16)a0[1]; a[2] = (bf16)a0[2]; a[3] = (bf16)a0[3];
        a[4] = (bf16)a1[0]; a[5] = (bf16)a1[1]; a[6] = (bf16)a1[2]; a[7] = (bf16)a1[3];
#pragma unroll
        for (int n = 0; n < 16; ++n) {
            const bf16x8 b = *(const bf16x8*)(wt + (size_t)(n * 16 + am) * D + kb);
            acc[n] = __builtin_amdgcn_mfma_f32_16x16x32_bf16(a, b, acc[n], 0, 0, 0);
        }
    }

    const int drow = row0 + ag * 4;
#pragma unroll
    for (int r = 0; r < 4; ++r) {
        if (drow + r < NNODES) {
            bf16* hp = h + (size_t)(drow + r) * D + am;
#pragma unroll
            for (int n = 0; n < 16; ++n) hp[n * 16] = (bf16)acc[n][r];
        }
    }
}

__device__ void dev_sortB(int b, const u64* __restrict__ binned, const int* __restrict__ bcur,
                          u32* __restrict__ sorted, int* __restrict__ rstart,
                          int* __restrict__ rcnt) {
    __shared__ int histB[256];
    __shared__ int scnB[256];
    const int tid = threadIdx.x;
    __syncthreads();
    const int cnt_b = min(bcur[b], BCAP);
    const u64* src = binned + (size_t)b * BCAP;

    histB[tid] = 0;
    __syncthreads();
    for (int i = tid; i < cnt_b; i += 256)
        atomicAdd(&histB[(int)((src[i] >> 16) & 255)], 1);
    __syncthreads();
    const int v = histB[tid];
    scnB[tid] = v;
    __syncthreads();
    for (int d = 1; d < 256; d <<= 1) {
        const int t = (tid >= d) ? scnB[tid - d] : 0;
        __syncthreads();
        scnB[tid] += t;
        __syncthreads();
    }
    const int excl = scnB[tid] - v;
    const int r = b * 256 + tid;
    if (r < NNODES) {
        rstart[r] = b * BCAP + excl;
        rcnt[r]   = v;
    }
    histB[tid] = excl;   // reuse as per-row cursor
    __syncthreads();
    for (int i = tid; i < cnt_b; i += 256) {
        const u64 rec = src[i];
        const int k = atomicAdd(&histB[(int)((rec >> 16) & 255)], 1);
        const float vf = __uint_as_float((u32)(rec >> 32));
        const u32 vb = __float_as_uint((float)(bf16)vf) & 0xffff0000u;  // RNE bf16
        sorted[(size_t)b * BCAP + k] = (u32)(rec & 0xFFFF) | vb;
    }
}

// ---------------------------------------------------------------------------
// Mega cooperative kernel: P0 prep -> sync -> P1 {binA || gemm} -> sync -> P2 sortB
// ---------------------------------------------------------------------------
__global__ __launch_bounds__(256, 2) void mega_kernel(const float* __restrict__ x,
                                                      const float* __restrict__ w,
                                                      const int* __restrict__ rows,
                                                      const int* __restrict__ cols,
                                                      const float* __restrict__ vals,
                                                      bf16* __restrict__ wt,
                                                      int* __restrict__ bcur,
                                                      u64* __restrict__ binned,
                                                      u32* __restrict__ sorted,
                                                      int* __restrict__ rstart,
                                                      int* __restrict__ rcnt,
                                                      bf16* __restrict__ h,
                                                      int E, int AB, int GB) {
    cg::grid_group grid = cg::this_grid();
    const int G = gridDim.x;

    for (int u = blockIdx.x; u < 17; u += G)
        dev_prep_unit(u, w, wt, bcur);
    grid.sync();

    for (int u = blockIdx.x; u < AB + GB; u += G) {
        if (u < AB) dev_binA(u, rows, cols, vals, bcur, binned, E);
        else        dev_gemm(u - AB, x, wt, h);
    }
    grid.sync();

    for (int b = blockIdx.x; b < NB; b += G)
        dev_sortB(b, binned, bcur, sorted, rstart, rcnt);
}

// ---------------------------------------------------------------------------
// Fallback wrappers (exactly the proven round-15 sequence)
// ---------------------------------------------------------------------------
__global__ __launch_bounds__(256) void fb_prep(const float* __restrict__ w,
                                               bf16* __restrict__ wt, int* __restrict__ bcur) {
    dev_prep_unit(blockIdx.x, w, wt, bcur);
}

__global__ __launch_bounds__(256) void fb_gemm_binA(const float* __restrict__ x,
                                                    const bf16* __restrict__ wt,
                                                    bf16* __restrict__ h,
                                                    const int* __restrict__ rows,
                                                    const int* __restrict__ cols,
                                                    const float* __restrict__ vals,
                                                    int* __restrict__ bcur,
                                                    u64* __restrict__ binned,
                                                    int AB, int E) {
    if ((int)blockIdx.x < AB) dev_binA(blockIdx.x, rows, cols, vals, bcur, binned, E);
    else                      dev_gemm(blockIdx.x - AB, x, wt, h);
}

__global__ __launch_bounds__(256) void fb_sortB(const u64* __restrict__ binned,
                                                const int* __restrict__ bcur,
                                                u32* __restrict__ sorted,
                                                int* __restrict__ rstart,
                                                int* __restrict__ rcnt) {
    dev_sortB(blockIdx.x, binned, bcur, sorted, rstart, rcnt);
}

// ---------------------------------------------------------------------------
// K3: per-row fused SpMM(bf16 h, CSR-u32) + bias + ELU + LayerNorm + expand
// one wave per row; lane l owns dims [4l, 4l+3]  (round-15 validated body)
// ---------------------------------------------------------------------------
__global__ __launch_bounds__(256) void row_kernel(const unsigned short* __restrict__ hb,
                                                  const int* __restrict__ rstart,
                                                  const int* __restrict__ rcnt,
                                                  const u32* __restrict__ ep,
                                                  const float* __restrict__ bias,
                                                  const float* __restrict__ gamma,
                                                  const float* __restrict__ beta,
                                                  const float* __restrict__ mask,
                                                  float* __restrict__ out, int n) {
    const int wave = threadIdx.x >> 6;
    const int lane = threadIdx.x & 63;
    const int r = blockIdx.x * 4 + wave;
    if (r >= n) return;

    const int s = rstart[r];
    const int e = s + rcnt[r];

    float a0 = 0.f, a1 = 0.f, a2 = 0.f, a3 = 0.f;
    int i = s;
    for (; i + 3 < e; i += 4) {
        const u32 e0 = ep[i], e1 = ep[i + 1], e2 = ep[i + 2], e3 = ep[i + 3];
        const uint2 q0 = *(const uint2*)(hb + (size_t)(e0 & 0xFFFF) * D + lane * 4);
        const uint2 q1 = *(const uint2*)(hb + (size_t)(e1 & 0xFFFF) * D + lane * 4);
        const uint2 q2 = *(const uint2*)(hb + (size_t)(e2 & 0xFFFF) * D + lane * 4);
        const uint2 q3 = *(const uint2*)(hb + (size_t)(e3 & 0xFFFF) * D + lane * 4);
        const float v0 = bfhi(e0), v1 = bfhi(e1), v2 = bfhi(e2), v3 = bfhi(e3);
        a0 += v0 * bflo(q0.x) + v1 * bflo(q1.x) + v2 * bflo(q2.x) + v3 * bflo(q3.x);
        a1 += v0 * bfhi(q0.x) + v1 * bfhi(q1.x) + v2 * bfhi(q2.x) + v3 * bfhi(q3.x);
        a2 += v0 * bflo(q0.y) + v1 * bflo(q1.y) + v2 * bflo(q2.y) + v3 * bflo(q3.y);
        a3 += v0 * bfhi(q0.y) + v1 * bfhi(q1.y) + v2 * bfhi(q2.y) + v3 * bfhi(q3.y);
    }
    for (; i < e; ++i) {
        const u32 e0 = ep[i];
        const uint2 q0 = *(const uint2*)(hb + (size_t)(e0 & 0xFFFF) * D + lane * 4);
        const float v0 = bfhi(e0);
        a0 += v0 * bflo(q0.x);
        a1 += v0 * bfhi(q0.x);
        a2 += v0 * bflo(q0.y);
        a3 += v0 * bfhi(q0.y);
    }

    // bias + ELU
    const f32x4 b4 = *(const f32x4*)(bias + lane * 4);
    float x0 = a0 + b4[0], x1 = a1 + b4[1], x2 = a2 + b4[2], x3 = a3 + b4[3];
    x0 = x0 > 0.f ? x0 : expm1f(x0);
    x1 = x1 > 0.f ? x1 : expm1f(x1);
    x2 = x2 > 0.f ? x2 : expm1f(x2);
    x3 = x3 > 0.f ? x3 : expm1f(x3);

    // LayerNorm over 256 dims
    float s1 = x0 + x1 + x2 + x3;
    float s2 = x0 * x0 + x1 * x1 + x2 * x2 + x3 * x3;
#pragma unroll
    for (int d = 1; d < 64; d <<= 1) {
        s1 += __shfl_xor(s1, d);
        s2 += __shfl_xor(s2, d);
    }
    const float mu   = s1 * (1.f / 256.f);
    const float var  = s2 * (1.f / 256.f) - mu * mu;
    const float rsig = rsqrtf(var + LN_EPS);

    const f32x4 g4  = *(const f32x4*)(gamma + lane * 4);
    const f32x4 be4 = *(const f32x4*)(beta + lane * 4);
    const float y0 = (x0 - mu) * rsig * g4[0] + be4[0];
    const float y1 = (x1 - mu) * rsig * g4[1] + be4[1];
    const float y2 = (x2 - mu) * rsig * g4[2] + be4[2];
    const float y3 = (x3 - mu) * rsig * g4[3] + be4[3];

#pragma unroll
    for (int smp = 0; smp < NSAMP; ++smp) {
        const f32x4 m4 = *(const f32x4*)(mask + smp * D + lane * 4);
        f32x4 o;
        o[0] = y0 * m4[0];
        o[1] = y1 * m4[1];
        o[2] = y2 * m4[2];
        o[3] = y3 * m4[3];
        __builtin_nontemporal_store(o, (f32x4*)(out + ((size_t)r * NSAMP + smp) * D + lane * 4));
    }
}

// ---------------------------------------------------------------------------
extern "C" void kernel_launch(void* const* d_in, const int* in_sizes, int n_in,
                              void* d_out, int out_size, void* d_ws, size_t ws_size,
                              hipStream_t stream) {
    const float* x     = (const float*)d_in[0];
    const int*   adj   = (const int*)d_in[1];   // [2][E]: rows then cols
    const float* vals  = (const float*)d_in[2];
    const float* mask  = (const float*)d_in[3];
    const float* w     = (const float*)d_in[4];
    const float* bias  = (const float*)d_in[5];
    const float* gamma = (const float*)d_in[6];
    const float* beta  = (const float*)d_in[7];
    float*       out   = (float*)d_out;

    const int N = NNODES;
    const int E = in_sizes[2];
    const int GB = (N + 63) / 64;                 // gemm units (782)
    const int AB = (E + ACHUNK - 1) / ACHUNK;     // binA units (196)
    const int* rows = adj;
    const int* cols = adj + E;

    // workspace layout: 25.6 + 7.23 + 14.45 + 0.13 + 0.4 = ~47.8 MB
    char* ws = (char*)d_ws;
    unsigned short* hb     = (unsigned short*)ws;                       // 25.6 MB
    u32*            sorted = (u32*)(hb + (size_t)N * D);                // 7.23 MB
    u64*            binned = (u64*)(sorted + (size_t)NB * BCAP);        // 14.45 MB
    bf16*           wt     = (bf16*)(binned + (size_t)NB * BCAP);       // 128 KB
    int*            bcur   = (int*)((char*)wt + (size_t)D * D * 2);     // 1 KB
    int*            rstart = bcur + 256;                                // 200 KB
    int*            rcnt   = rstart + N;                                // 200 KB
    bf16*           hbf    = (bf16*)hb;

    // cooperative grid size: co-resident by construction (deterministic per process)
    int maxB = 0;
    hipError_t occ = hipOccupancyMaxActiveBlocksPerMultiprocessor(&maxB, mega_kernel, 256, 0);
    int G = 512;
    if (occ == hipSuccess && maxB >= 1) {
        const long cap = (long)maxB * 256;        // 256 CUs on MI355X
        if (cap < G) G = (int)cap;
    } else {
        G = 256;
    }

    int   Ev = E, ABv = AB, GBv = GB;
    void* args[] = {(void*)&x, (void*)&w, (void*)&rows, (void*)&cols, (void*)&vals,
                    (void*)&wt, (void*)&bcur, (void*)&binned, (void*)&sorted,
                    (void*)&rstart, (void*)&rcnt, (void*)&hbf,
                    (void*)&Ev, (void*)&ABv, (void*)&GBv};

    hipError_t rc = hipLaunchCooperativeKernel(mega_kernel, dim3(G), dim3(256),
                                               args, 0, stream);
    if (rc != hipSuccess) {
        // deterministic fallback: proven round-15 sequence
        fb_prep<<<17, 256, 0, stream>>>(w, wt, bcur);
        fb_gemm_binA<<<AB + GB, 256, 0, stream>>>(x, wt, hbf, rows, cols, vals,
                                                  bcur, binned, AB, E);
        fb_sortB<<<NB, 256, 0, stream>>>(binned, bcur, sorted, rstart, rcnt);
    }
    row_kernel<<<(N + 3) / 4, 256, 0, stream>>>(hb, rstart, rcnt, sorted,
                                                bias, gamma, beta, mask, out, N);
}

// Round 17
// 245.155 us; speedup vs baseline: 1.2666x; 1.2666x over previous
//
#include <hip/hip_runtime.h>
#include <math.h>

#define NNODES 50000
#define D 256
#define NSAMP 5
#define LN_EPS 1e-5f
#define NB 196           // row buckets of 256 rows: ceil(50000/256)
#define BCAP 9216        // edges per bucket capacity (mean 8192, +11 sigma)
#define ACHUNK 4096      // edges per binA block (391 blocks -> all CUs busy)
#define PREPB 16         // prep transpose blocks

typedef __bf16 bf16;
typedef __attribute__((ext_vector_type(8))) __bf16 bf16x8;
typedef __attribute__((ext_vector_type(4))) float f32x4;
typedef unsigned long long u64;
typedef unsigned int u32;

__device__ inline float bflo(u32 u) { return __uint_as_float(u << 16); }
__device__ inline float bfhi(u32 u) { return __uint_as_float(u & 0xffff0000u); }

__device__ inline u64 packrec(int r, int c, float v) {
    // col:16 | row:16 | valbits:32   (N=50000 < 65536 so both fit 16 bits)
    return (u64)(u32)(c | (r << 16)) | ((u64)__float_as_uint(v) << 32);
}

// ---------------------------------------------------------------------------
// K1 (fused, 512 thr): blocks [0,16): w transpose fp32->bf16 (64x64 LDS tiles)
//                      blocks [16, 16+AB): binA bucket binning
// wt is only read by the NEXT dispatch, so no intra-dispatch ordering needed.
// ---------------------------------------------------------------------------
__global__ __launch_bounds__(512) void prep_binA_kernel(const float* __restrict__ w,
                                                        bf16* __restrict__ wt,
                                                        const int* __restrict__ rows,
                                                        const int* __restrict__ cols,
                                                        const float* __restrict__ vals,
                                                        int* __restrict__ bcur,
                                                        u64* __restrict__ binned, int E) {
    if ((int)blockIdx.x < PREPB) {
        __shared__ float t[64][65];
        const int bi = blockIdx.x >> 2;     // k-tile
        const int bj = blockIdx.x & 3;      // n-tile
        const int tid = threadIdx.x;
        const int rr = tid >> 6;            // 0..7
        const int cc = tid & 63;
#pragma unroll
        for (int it = 0; it < 8; ++it) {
            const int krow = rr + it * 8;
            t[krow][cc] = w[(size_t)(bi * 64 + krow) * D + (bj * 64 + cc)];
        }
        __syncthreads();
#pragma unroll
        for (int it = 0; it < 8; ++it) {
            const int nrow = rr + it * 8;
            wt[(size_t)(bj * 64 + nrow) * D + (bi * 64 + cc)] = (bf16)t[cc][nrow];
        }
        return;
    }

    // ---- binA path ----
    __shared__ int hist[NB];
    __shared__ int base[NB];
    for (int i = threadIdx.x; i < NB; i += 512) hist[i] = 0;
    __syncthreads();
    const int e0 = (blockIdx.x - PREPB) * ACHUNK;
    const int e1 = min(e0 + ACHUNK, E);
    for (int e = e0 + threadIdx.x; e < e1; e += 512)
        atomicAdd(&hist[rows[e] >> 8], 1);
    __syncthreads();
    for (int i = threadIdx.x; i < NB; i += 512) {
        const int c = hist[i];
        base[i] = c ? atomicAdd(&bcur[i], c) : 0;
        hist[i] = 0;                      // reuse as local cursor
    }
    __syncthreads();
    for (int e = e0 + threadIdx.x; e < e1; e += 512) {
        const int r = rows[e];
        const int b = r >> 8;
        const int k = base[b] + atomicAdd(&hist[b], 1);
        if (k < BCAP)                     // statistically unreachable guard
            binned[(size_t)b * BCAP + k] = packrec(r, cols[e], vals[e]);
    }
}

// ---------------------------------------------------------------------------
// K2 (fused): blocks [0, NB): sortB — per-bucket counting sort by row,
//             emitting u32 records (col | bf16val); blocks [NB,NB+GB): GEMM.
// sortB (latency/LDS) and GEMM (MFMA/HBM) are independent -> complementary.
// ---------------------------------------------------------------------------
__global__ __launch_bounds__(256) void gemm_sortB_kernel(const float* __restrict__ x,
                                                         const bf16* __restrict__ wt,
                                                         bf16* __restrict__ h,
                                                         const u64* __restrict__ binned,
                                                         const int* __restrict__ bcur,
                                                         u32* __restrict__ sorted,
                                                         int* __restrict__ rstart,
                                                         int* __restrict__ rcnt) {
    if ((int)blockIdx.x < NB) {
        const int b = blockIdx.x;
        const int tid = threadIdx.x;
        const int cnt_b = min(bcur[b], BCAP);
        const u64* src = binned + (size_t)b * BCAP;

        __shared__ int hist[256];
        __shared__ int scn[256];
        hist[tid] = 0;
        __syncthreads();
        for (int i = tid; i < cnt_b; i += 256)
            atomicAdd(&hist[(int)((src[i] >> 16) & 255)], 1);
        __syncthreads();
        const int v = hist[tid];
        scn[tid] = v;
        __syncthreads();
        for (int d = 1; d < 256; d <<= 1) {
            const int t = (tid >= d) ? scn[tid - d] : 0;
            __syncthreads();
            scn[tid] += t;
            __syncthreads();
        }
        const int excl = scn[tid] - v;
        const int r = b * 256 + tid;
        if (r < NNODES) {
            rstart[r] = b * BCAP + excl;
            rcnt[r]   = v;
        }
        hist[tid] = excl;   // reuse as per-row cursor
        __syncthreads();
        for (int i = tid; i < cnt_b; i += 256) {
            const u64 rec = src[i];
            const int k = atomicAdd(&hist[(int)((rec >> 16) & 255)], 1);
            const float vf = __uint_as_float((u32)(rec >> 32));
            const u32 vb = __float_as_uint((float)(bf16)vf) & 0xffff0000u;  // RNE bf16
            sorted[(size_t)b * BCAP + k] = (u32)(rec & 0xFFFF) | vb;
        }
        return;
    }

    // ---- GEMM path (identical to validated round-2 kernel) ----
    const int gb = blockIdx.x - NB;
    const int wave = threadIdx.x >> 6;
    const int lane = threadIdx.x & 63;
    const int row0 = gb * 64 + wave * 16;
    const int am = lane & 15;
    const int ag = lane >> 4;

    int arow = row0 + am;
    if (arow >= NNODES) arow = NNODES - 1;

    f32x4 acc[16];
#pragma unroll
    for (int n = 0; n < 16; ++n) acc[n] = (f32x4){0.f, 0.f, 0.f, 0.f};

#pragma unroll
    for (int kk = 0; kk < 8; ++kk) {
        const int kb = kk * 32 + ag * 8;
        const float* xp = x + (size_t)arow * D + kb;
        const f32x4 a0 = __builtin_nontemporal_load((const f32x4*)xp);
        const f32x4 a1 = __builtin_nontemporal_load((const f32x4*)(xp + 4));
        bf16x8 a;
        a[0] = (bf16)a0[0]; a[1] = (bf16)a0[1]; a[2] = (bf16)a0[2]; a[3] = (bf16)a0[3];
        a[4] = (bf16)a1[0]; a[5] = (bf16)a1[1]; a[6] = (bf16)a1[2]; a[7] = (bf16)a1[3];
#pragma unroll
        for (int n = 0; n < 16; ++n) {
            const bf16x8 b = *(const bf16x8*)(wt + (size_t)(n * 16 + am) * D + kb);
            acc[n] = __builtin_amdgcn_mfma_f32_16x16x32_bf16(a, b, acc[n], 0, 0, 0);
        }
    }

    const int drow = row0 + ag * 4;
#pragma unroll
    for (int r = 0; r < 4; ++r) {
        if (drow + r < NNODES) {
            bf16* hp = h + (size_t)(drow + r) * D + am;
#pragma unroll
            for (int n = 0; n < 16; ++n) hp[n * 16] = (bf16)acc[n][r];
        }
    }
}

// ---------------------------------------------------------------------------
// K3: per-row fused SpMM(bf16 h, CSR-u32) + bias + ELU + LayerNorm + expand
// one wave per row; lane l owns dims [4l, 4l+3]  (round-15 validated body)
// ---------------------------------------------------------------------------
__global__ __launch_bounds__(256) void row_kernel(const unsigned short* __restrict__ hb,
                                                  const int* __restrict__ rstart,
                                                  const int* __restrict__ rcnt,
                                                  const u32* __restrict__ ep,
                                                  const float* __restrict__ bias,
                                                  const float* __restrict__ gamma,
                                                  const float* __restrict__ beta,
                                                  const float* __restrict__ mask,
                                                  float* __restrict__ out, int n) {
    const int wave = threadIdx.x >> 6;
    const int lane = threadIdx.x & 63;
    const int r = blockIdx.x * 4 + wave;
    if (r >= n) return;

    const int s = rstart[r];
    const int e = s + rcnt[r];

    float a0 = 0.f, a1 = 0.f, a2 = 0.f, a3 = 0.f;
    int i = s;
    for (; i + 3 < e; i += 4) {
        const u32 e0 = ep[i], e1 = ep[i + 1], e2 = ep[i + 2], e3 = ep[i + 3];
        const uint2 q0 = *(const uint2*)(hb + (size_t)(e0 & 0xFFFF) * D + lane * 4);
        const uint2 q1 = *(const uint2*)(hb + (size_t)(e1 & 0xFFFF) * D + lane * 4);
        const uint2 q2 = *(const uint2*)(hb + (size_t)(e2 & 0xFFFF) * D + lane * 4);
        const uint2 q3 = *(const uint2*)(hb + (size_t)(e3 & 0xFFFF) * D + lane * 4);
        const float v0 = bfhi(e0), v1 = bfhi(e1), v2 = bfhi(e2), v3 = bfhi(e3);
        a0 += v0 * bflo(q0.x) + v1 * bflo(q1.x) + v2 * bflo(q2.x) + v3 * bflo(q3.x);
        a1 += v0 * bfhi(q0.x) + v1 * bfhi(q1.x) + v2 * bfhi(q2.x) + v3 * bfhi(q3.x);
        a2 += v0 * bflo(q0.y) + v1 * bflo(q1.y) + v2 * bflo(q2.y) + v3 * bflo(q3.y);
        a3 += v0 * bfhi(q0.y) + v1 * bfhi(q1.y) + v2 * bfhi(q2.y) + v3 * bfhi(q3.y);
    }
    for (; i < e; ++i) {
        const u32 e0 = ep[i];
        const uint2 q0 = *(const uint2*)(hb + (size_t)(e0 & 0xFFFF) * D + lane * 4);
        const float v0 = bfhi(e0);
        a0 += v0 * bflo(q0.x);
        a1 += v0 * bfhi(q0.x);
        a2 += v0 * bflo(q0.y);
        a3 += v0 * bfhi(q0.y);
    }

    // bias + ELU
    const f32x4 b4 = *(const f32x4*)(bias + lane * 4);
    float x0 = a0 + b4[0], x1 = a1 + b4[1], x2 = a2 + b4[2], x3 = a3 + b4[3];
    x0 = x0 > 0.f ? x0 : expm1f(x0);
    x1 = x1 > 0.f ? x1 : expm1f(x1);
    x2 = x2 > 0.f ? x2 : expm1f(x2);
    x3 = x3 > 0.f ? x3 : expm1f(x3);

    // LayerNorm over 256 dims
    float s1 = x0 + x1 + x2 + x3;
    float s2 = x0 * x0 + x1 * x1 + x2 * x2 + x3 * x3;
#pragma unroll
    for (int d = 1; d < 64; d <<= 1) {
        s1 += __shfl_xor(s1, d);
        s2 += __shfl_xor(s2, d);
    }
    const float mu   = s1 * (1.f / 256.f);
    const float var  = s2 * (1.f / 256.f) - mu * mu;
    const float rsig = rsqrtf(var + LN_EPS);

    const f32x4 g4  = *(const f32x4*)(gamma + lane * 4);
    const f32x4 be4 = *(const f32x4*)(beta + lane * 4);
    const float y0 = (x0 - mu) * rsig * g4[0] + be4[0];
    const float y1 = (x1 - mu) * rsig * g4[1] + be4[1];
    const float y2 = (x2 - mu) * rsig * g4[2] + be4[2];
    const float y3 = (x3 - mu) * rsig * g4[3] + be4[3];

#pragma unroll
    for (int smp = 0; smp < NSAMP; ++smp) {
        const f32x4 m4 = *(const f32x4*)(mask + smp * D + lane * 4);
        f32x4 o;
        o[0] = y0 * m4[0];
        o[1] = y1 * m4[1];
        o[2] = y2 * m4[2];
        o[3] = y3 * m4[3];
        __builtin_nontemporal_store(o, (f32x4*)(out + ((size_t)r * NSAMP + smp) * D + lane * 4));
    }
}

// ---------------------------------------------------------------------------
extern "C" void kernel_launch(void* const* d_in, const int* in_sizes, int n_in,
                              void* d_out, int out_size, void* d_ws, size_t ws_size,
                              hipStream_t stream) {
    const float* x     = (const float*)d_in[0];
    const int*   adj   = (const int*)d_in[1];   // [2][E]: rows then cols
    const float* vals  = (const float*)d_in[2];
    const float* mask  = (const float*)d_in[3];
    const float* w     = (const float*)d_in[4];
    const float* bias  = (const float*)d_in[5];
    const float* gamma = (const float*)d_in[6];
    const float* beta  = (const float*)d_in[7];
    float*       out   = (float*)d_out;

    const int N = NNODES;
    const int E = in_sizes[2];
    const int GB = (N + 63) / 64;                 // gemm blocks (782)
    const int AB = (E + ACHUNK - 1) / ACHUNK;     // binA blocks (391)

    // workspace layout: 25.6 + 7.23 + 14.45 + 0.13 + 0.4 = ~47.8 MB
    char* ws = (char*)d_ws;
    unsigned short* hb     = (unsigned short*)ws;                       // 25.6 MB
    u32*            sorted = (u32*)(hb + (size_t)N * D);                // 7.23 MB
    u64*            binned = (u64*)(sorted + (size_t)NB * BCAP);        // 14.45 MB
    bf16*           wt     = (bf16*)(binned + (size_t)NB * BCAP);       // 128 KB
    int*            bcur   = (int*)((char*)wt + (size_t)D * D * 2);     // 1 KB
    int*            rstart = bcur + 256;                                // 200 KB
    int*            rcnt   = rstart + N;                                // 200 KB

    hipMemsetAsync(bcur, 0, 256 * sizeof(int), stream);
    prep_binA_kernel<<<PREPB + AB, 512, 0, stream>>>(w, wt, adj, adj + E, vals,
                                                     bcur, binned, E);
    gemm_sortB_kernel<<<NB + GB, 256, 0, stream>>>(x, wt, (bf16*)hb,
                                                   binned, bcur, sorted, rstart, rcnt);
    row_kernel<<<(N + 3) / 4, 256, 0, stream>>>(hb, rstart, rcnt, sorted,
                                                bias, gamma, beta, mask, out, N);
}